// Round 4
// baseline (83.798 us; speedup 1.0000x reference)
//
#include <hip/hip_runtime.h>
#include <math.h>

#define EPSF     1.1920928955078125e-07f   // float32 eps
#define BYPASSF  0.9999998807907104f       // 1 - eps
#define CLAMPF   1e30f
#define NBATCH   32768

// split constants
#define INV2PI_HI 0.15915493667125701904f  // fp32(1/2pi)
#define INV2PI_LO 6.42063831e-9f           // 1/2pi - hi
#define L2E_HI    1.44269502162933349609f  // fp32(log2 e)
#define L2E_LO    1.92596299e-8f           // log2e - hi
#define LN2F      0.69314718055994530942f
#define PI_F      3.14159274101257324219f
#define PIO2_F    1.57079637050628662109f

// fast-path geometry: 16 subtrees/element, depth-6 local fold
#define SLAB_SRC 504                       // floats per subtree slab in d_ws (63 steps * 8)
#define SLAB_LDS 508                       // floats per slab in LDS (bank skew: start banks step 4)
#define GDS_FLOATS (16 * SLAB_LDS + 120)   // + 15 top gates * 8 = 8248 floats = 32,992 B
#define WS_LEAF_F4 1024                    // leaf table float4 count
#define WS_NEED ((4096 + 8184) * 4)        // bytes: leaves + gates

struct C2 { float r, i; };

__device__ __forceinline__ float fixv(float v) {
  float c = fminf(fmaxf(v, -CLAMPF), CLAMPF);
  return (v != v) ? 0.0f : c;
}

__device__ __attribute__((noinline)) float2 slow_sincos(float y) {
  return make_float2(sinf(y), cosf(y));
}

__device__ __forceinline__ void softmax3_store(float a, float b, float c, float* out) {
  float m = fmaxf(a, fmaxf(b, c));
  float e0 = expf(a - m), e1 = expf(b - m), e2 = expf(c - m);
  float s = (e0 + e1) + e2;
  out[0] = e0 / s; out[1] = e1 / s; out[2] = e2 / s;
}

__device__ __forceinline__ void softmax4(const float* __restrict__ in, float* out) {
  float a = in[0], b = in[1], c = in[2], d = in[3];
  float m = fmaxf(fmaxf(a, b), fmaxf(c, d));
  float e0 = expf(a - m), e1 = expf(b - m), e2 = expf(c - m), e3 = expf(d - m);
  float s = ((e0 + e1) + e2) + e3;
  out[0] = e0 / s; out[1] = e1 / s; out[2] = e2 / s; out[3] = e3 / s;
}

// bypass/eps folding (exact: probs sum to 1 -> at most one can exceed 1-eps)
__device__ __forceinline__ void fold_gate(float* p) {
  if (p[3] <= EPSF) p[3] = 0.0f;
  if (p[0] > BYPASSF)      { p[0]=1.f; p[1]=0.f; p[2]=0.f; p[3]=0.f; }
  else if (p[1] > BYPASSF) { p[0]=0.f; p[1]=1.f; p[2]=0.f; p[3]=0.f; }
  else if (p[2] > BYPASSF) { p[0]=0.f; p[1]=0.f; p[2]=1.f; p[3]=0.f; }
}

__device__ __forceinline__ float exp_core(float xe, int* n_out) {
  float nf = rintf(xe * 1.4426950408889634f);
  float f  = fmaf(xe, L2E_HI, -nf);
  f        = fmaf(xe, L2E_LO, f);
  *n_out   = (int)nf;
  return __builtin_amdgcn_exp2f(f);
}

// clamp(cexp(blend(gl, L)) - clog(blend(gr, R))) -- general complex path
__device__ __forceinline__ C2 combine2(const float* __restrict__ g8, C2 L, C2 R, float x0, float x1) {
  float4 gl = *(const float4*)(g8);
  float4 gr = *(const float4*)(g8 + 4);
  float lr_ = fmaf(gl.w, L.r, gl.x) + fmaf(gl.z, x1, gl.y * x0);
  float li_ = gl.w * L.i;
  float rr_ = fmaf(gr.w, R.r, gr.x) + fmaf(gr.z, x1, gr.y * x0);
  float ri_ = gr.w * R.i;

  // sincos via revolution-domain Cody-Waite feeding HW v_sin/v_cos
  float sy, cy;
  {
    float nf = rintf(li_ * 0.15915494309189535f);
    float rv = fmaf(li_, INV2PI_HI, -nf);
    rv       = fmaf(li_, INV2PI_LO, rv);
    sy = __builtin_amdgcn_sinf(rv);
    cy = __builtin_amdgcn_cosf(rv);
    if (fabsf(li_) > 20000.0f) { float2 sc = slow_sincos(li_); sy = sc.x; cy = sc.y; }
  }

  // exp(lr_) scaled: covers ldexp_cexpf region and over/underflow
  float xe = fminf(fmaxf(lr_, -200.0f), 200.0f);
  int ne;
  float eh = exp_core(xe, &ne);
  float er = __builtin_amdgcn_ldexpf(eh * cy, ne);
  float ei = __builtin_amdgcn_ldexpf(eh * sy, ne);

  // clog: shared s = mn/mx for log-hypot and atan2
  float ax = fabsf(rr_), ay = fabsf(ri_);
  float mx = fmaxf(ax, ay), mn = fminf(ax, ay);
  float s  = (mx == 0.0f) ? 0.0f : mn * __builtin_amdgcn_rcpf(mx);
  float z  = s * s;
  float lr = LN2F * fmaf(0.5f, __builtin_amdgcn_logf(z + 1.0f), __builtin_amdgcn_logf(mx));
  float u =              0.00282363896f;
  u = fmaf(u, z, -0.0159569028f);
  u = fmaf(u, z,  0.0425049886f);
  u = fmaf(u, z, -0.0748900920f);
  u = fmaf(u, z,  0.1063479334f);
  u = fmaf(u, z, -0.1420273631f);
  u = fmaf(u, z,  0.1999269574f);
  u = fmaf(u, z, -0.3333310186f);
  float at = fmaf(s * z, u, s);
  at = (ay > ax)    ? (PIO2_F - at) : at;
  at = (rr_ < 0.0f) ? (PI_F   - at) : at;
  float li = copysignf(at, ri_);

  C2 o; o.r = fixv(er - lr); o.i = fixv(ei - li);
  return o;
}

// level-1 specialization: both children are real leaves (imag exactly 0)
__device__ __forceinline__ C2 combine_l1(const float* __restrict__ g8, float Lr, float Rr,
                                         float x0, float x1) {
  float4 gl = *(const float4*)(g8);
  float4 gr = *(const float4*)(g8 + 4);
  float lr_ = fmaf(gl.w, Lr, gl.x) + fmaf(gl.z, x1, gl.y * x0);
  float rr_ = fmaf(gr.w, Rr, gr.x) + fmaf(gr.z, x1, gr.y * x0);

  float xe = fminf(fmaxf(lr_, -200.0f), 200.0f);
  int ne;
  float eh = exp_core(xe, &ne);
  float er = __builtin_amdgcn_ldexpf(eh, ne);

  float lr = LN2F * __builtin_amdgcn_logf(fabsf(rr_));
  C2 o;
  o.r = fminf(fmaxf(er - lr, -CLAMPF), CLAMPF);
  o.i = (rr_ < 0.0f) ? -PI_F : 0.0f;
  return o;
}

// ---------------- prep: softmax + fold + DFS reorder into d_ws, plus probs outputs ----------------
__global__ __launch_bounds__(256) void prep_kernel(
    const float* __restrict__ leaf_logits,
    const float* __restrict__ gate_logits,
    float* __restrict__ out_leaf,   // 1024 x 3 raw
    float* __restrict__ out_gate,   // 2046 x 4 raw
    float* __restrict__ ws_leaf,    // 1024 float4 {w0,w1,w2,0}
    float* __restrict__ ws_gate) {  // 16*504 (DFS levels 1..6) + 15*8 (top)
  int i = blockIdx.x * 256 + threadIdx.x;
  if (i < 1024) {
    float p[3];
    softmax3_store(leaf_logits[i * 3], leaf_logits[i * 3 + 1], leaf_logits[i * 3 + 2], p);
    out_leaf[i * 3] = p[0]; out_leaf[i * 3 + 1] = p[1]; out_leaf[i * 3 + 2] = p[2];
    ((float4*)ws_leaf)[i] = make_float4(p[0], p[1], p[2], 0.0f);
  } else if (i < 1024 + 2046) {
    int j = i - 1024;                  // gate half-row 0..2045
    int g = j >> 1, half = j & 1;
    float p[4];
    softmax4(gate_logits + j * 4, p);
    ((float4*)out_gate)[j] = make_float4(p[0], p[1], p[2], p[3]);
    fold_gate(p);
    int di;
    if (g < 1008) {                    // levels 1..6 -> per-subtree DFS order
      int z  = 1024 - g;
      int k  = __clz(z - 1) - 21;      // 1..6
      int pp = g - (1024 - (2048 >> k));
      int t  = pp >> (6 - k);
      int pl = pp & ((1 << (6 - k)) - 1);
      int L  = ((pl + 1) << k) - 1;
      int step = L - __popc(L) + (k - 1);  // 0..62
      di = t * SLAB_SRC + step * 8;
    } else {
      di = 16 * SLAB_SRC + (g - 1008) * 8; // top 15 gates flat
    }
    ((float4*)(ws_gate + di))[half] = make_float4(p[0], p[1], p[2], p[3]);
  }
}

// ---------------- fast tree: 16 lanes/element, gates in LDS, leaves via L1 ----------------
__global__ __launch_bounds__(512, 8) void tree16_kernel(
    const float* __restrict__ x,
    const float* __restrict__ ws_leaf,
    const float* __restrict__ ws_gate,
    float* __restrict__ out0, int cplx) {

  __shared__ __align__(16) float gds[GDS_FLOATS];
  const int tid = threadIdx.x;

  // copy gate table ws -> LDS, re-striding slabs 504 -> 508 (126 -> 127 float4)
  {
    float4* g4 = (float4*)gds;
    const float4* s4 = (const float4*)ws_gate;
    for (int c = tid; c < 2016; c += 512) {
      int t = c / 126;
      int r = c - t * 126;
      g4[t * 127 + r] = s4[c];
    }
    if (tid < 30) g4[2032 + tid] = s4[2016 + tid];   // top gates
  }
  __syncthreads();

  const int gtid = blockIdx.x * 512 + tid;
  const int e  = gtid >> 4;          // batch element
  const int lt = tid & 15;           // subtree index
  const float2 xv = ((const float2*)x)[e];
  const float x0 = xv.x, x1 = xv.y;
  const float* gb = &gds[lt * SLAB_LDS];
  const float* tds = &gds[16 * SLAB_LDS];
  const float4* lwp = (const float4*)ws_leaf + lt * 64;

  C2 p1, p2, p3, p4, p5;             // pending left siblings, levels 2..6
  C2 res; res.r = 0.0f; res.i = 0.0f;
  int step = 0;

  #pragma unroll 2
  for (int h = 0; h < 32; ++h) {
    float4 w0 = lwp[2 * h];
    float4 w1 = lwp[2 * h + 1];
    float a = fmaf(w0.z, x1, fmaf(w0.y, x0, w0.x));
    float b = fmaf(w1.z, x1, fmaf(w1.y, x0, w1.x));
    C2 cur = combine_l1(gb + step * 8, a, b, x0, x1); step++;
    if (!(h & 1))  { p1 = cur; continue; }
    cur = combine2(gb + step * 8, p1, cur, x0, x1); step++;
    if (!(h & 2))  { p2 = cur; continue; }
    cur = combine2(gb + step * 8, p2, cur, x0, x1); step++;
    if (!(h & 4))  { p3 = cur; continue; }
    cur = combine2(gb + step * 8, p3, cur, x0, x1); step++;
    if (!(h & 8))  { p4 = cur; continue; }
    cur = combine2(gb + step * 8, p4, cur, x0, x1); step++;
    if (!(h & 16)) { p5 = cur; continue; }
    cur = combine2(gb + step * 8, p5, cur, x0, x1); step++;
    res = cur;                       // level-6 subtree root
  }

  // top 4 levels across the 16 lanes of this element (gate rows 1008..1022 -> tds 0..14)
  C2 v = res;
  { C2 o; o.r = __shfl_xor(v.r, 1); o.i = __shfl_xor(v.i, 1);
    C2 L = (lt & 1) ? o : v, R = (lt & 1) ? v : o;
    v = combine2(tds + (lt >> 1) * 8, L, R, x0, x1); }
  { C2 o; o.r = __shfl_xor(v.r, 2); o.i = __shfl_xor(v.i, 2);
    C2 L = (lt & 2) ? o : v, R = (lt & 2) ? v : o;
    v = combine2(tds + (8 + (lt >> 2)) * 8, L, R, x0, x1); }
  { C2 o; o.r = __shfl_xor(v.r, 4); o.i = __shfl_xor(v.i, 4);
    C2 L = (lt & 4) ? o : v, R = (lt & 4) ? v : o;
    v = combine2(tds + (12 + (lt >> 3)) * 8, L, R, x0, x1); }
  { C2 o; o.r = __shfl_xor(v.r, 8); o.i = __shfl_xor(v.i, 8);
    C2 L = (lt & 8) ? o : v, R = (lt & 8) ? v : o;
    v = combine2(tds + 14 * 8, L, R, x0, x1); }

  if (lt == 0) {
    if (cplx) { out0[2 * e] = v.r; out0[2 * e + 1] = v.i; }
    else      { out0[e] = v.r; }
  }
}

// ---------------- fallback (R3 kernels, used only if ws_size is too small) ----------------
#define GSTRIDE  1020
#define LSTRIDE  516

__device__ __forceinline__ void store_gate_fb(const float* __restrict__ in, float* __restrict__ out) {
  float p[4];
  softmax4(in, p);
  fold_gate(p);
  out[0]=p[0]; out[1]=p[1]; out[2]=p[2]; out[3]=p[3];
}

__global__ __launch_bounds__(512) void tree_fb_kernel(
    const float* __restrict__ x,
    const float* __restrict__ leaf_logits,
    const float* __restrict__ gate_logits,
    float* __restrict__ out0, int cplx) {

  __shared__ __align__(16) float gds[8 * GSTRIDE];
  __shared__ __align__(16) float tds[7 * 8];
  __shared__ __align__(16) float lw[8 * LSTRIDE];
  const int tid = threadIdx.x;

  for (int l = tid; l < 1024; l += 512) {
    float p[3];
    softmax3_store(leaf_logits[l * 3], leaf_logits[l * 3 + 1], leaf_logits[l * 3 + 2], p);
    *(float4*)&lw[(l >> 7) * LSTRIDE + (l & 127) * 4] = make_float4(p[0], p[1], p[2], 0.0f);
  }
  for (int g = tid; g < 1016; g += 512) {
    int z  = 1024 - g;
    int k  = __clz(z - 1) - 21;
    int p  = g - (1024 - (2048 >> k));
    int t  = p >> (7 - k);
    int pl = p & ((1 << (7 - k)) - 1);
    int L  = ((pl + 1) << k) - 1;
    int step = L - __popc(L) + (k - 1);
    float* dst = &gds[t * GSTRIDE + step * 8];
    store_gate_fb(gate_logits + g * 8,     dst);
    store_gate_fb(gate_logits + g * 8 + 4, dst + 4);
  }
  if (tid < 7) {
    int g = 1016 + tid;
    store_gate_fb(gate_logits + g * 8,     &tds[tid * 8]);
    store_gate_fb(gate_logits + g * 8 + 4, &tds[tid * 8 + 4]);
  }
  __syncthreads();

  const int gtid = blockIdx.x * 512 + tid;
  const int e  = gtid >> 3;
  const int lt = tid & 7;
  const float2 xv = ((const float2*)x)[e];
  const float x0 = xv.x, x1 = xv.y;
  const float* gb = &gds[lt * GSTRIDE];
  const float* lb = &lw[lt * LSTRIDE];

  C2 p1, p2, p3, p4, p5, p6;
  C2 res; res.r = 0.0f; res.i = 0.0f;
  int step = 0;

  #pragma unroll 2
  for (int h = 0; h < 64; ++h) {
    float4 w0 = *(const float4*)&lb[(2 * h) * 4];
    float4 w1 = *(const float4*)&lb[(2 * h + 1) * 4];
    float a = fmaf(w0.z, x1, fmaf(w0.y, x0, w0.x));
    float b = fmaf(w1.z, x1, fmaf(w1.y, x0, w1.x));
    C2 cur = combine_l1(gb + step * 8, a, b, x0, x1); step++;
    if (!(h & 1))  { p1 = cur; continue; }
    cur = combine2(gb + step * 8, p1, cur, x0, x1); step++;
    if (!(h & 2))  { p2 = cur; continue; }
    cur = combine2(gb + step * 8, p2, cur, x0, x1); step++;
    if (!(h & 4))  { p3 = cur; continue; }
    cur = combine2(gb + step * 8, p3, cur, x0, x1); step++;
    if (!(h & 8))  { p4 = cur; continue; }
    cur = combine2(gb + step * 8, p4, cur, x0, x1); step++;
    if (!(h & 16)) { p5 = cur; continue; }
    cur = combine2(gb + step * 8, p5, cur, x0, x1); step++;
    if (!(h & 32)) { p6 = cur; continue; }
    cur = combine2(gb + step * 8, p6, cur, x0, x1); step++;
    res = cur;
  }

  C2 v = res;
  { C2 o; o.r = __shfl_xor(v.r, 1); o.i = __shfl_xor(v.i, 1);
    C2 L = (lt & 1) ? o : v, R = (lt & 1) ? v : o;
    v = combine2(&tds[(lt >> 1) * 8], L, R, x0, x1); }
  { C2 o; o.r = __shfl_xor(v.r, 2); o.i = __shfl_xor(v.i, 2);
    C2 L = (lt & 2) ? o : v, R = (lt & 2) ? v : o;
    v = combine2(&tds[(4 + (lt >> 2)) * 8], L, R, x0, x1); }
  { C2 o; o.r = __shfl_xor(v.r, 4); o.i = __shfl_xor(v.i, 4);
    C2 L = (lt & 4) ? o : v, R = (lt & 4) ? v : o;
    v = combine2(&tds[6 * 8], L, R, x0, x1); }

  if (lt == 0) {
    if (cplx) { out0[2 * e] = v.r; out0[2 * e + 1] = v.i; }
    else      { out0[e] = v.r; }
  }
}

__global__ __launch_bounds__(256) void probs_fb_kernel(
    const float* __restrict__ leaf_logits,
    const float* __restrict__ gate_logits,
    float* __restrict__ out_leaf,
    float* __restrict__ out_gate) {
  int i = blockIdx.x * 256 + threadIdx.x;
  if (i < 1024) {
    softmax3_store(leaf_logits[i * 3], leaf_logits[i * 3 + 1], leaf_logits[i * 3 + 2],
                   &out_leaf[i * 3]);
  } else if (i < 1024 + 2046) {
    int j = i - 1024;
    float p[4];
    softmax4(gate_logits + j * 4, p);
    ((float4*)out_gate)[j] = make_float4(p[0], p[1], p[2], p[3]);
  }
}

extern "C" void kernel_launch(void* const* d_in, const int* in_sizes, int n_in,
                              void* d_out, int out_size, void* d_ws, size_t ws_size,
                              hipStream_t stream) {
  const float* x  = (const float*)d_in[0];   // (32768, 2)
  const float* ll = (const float*)d_in[1];   // (1024, 3)
  const float* gl = (const float*)d_in[2];   // (1023, 2, 4)
  float* out0 = (float*)d_out;

  int S = out_size - (3072 + 8184);          // complex chunk: 2*32768 interleaved or 32768 real
  int cplx = (S >= 2 * NBATCH) ? 1 : 0;
  float* out_leaf = out0 + S;
  float* out_gate = out_leaf + 3072;

  if (ws_size >= (size_t)WS_NEED) {
    float* ws_leaf = (float*)d_ws;           // 4096 floats
    float* ws_gate = ws_leaf + 4096;         // 8184 floats
    prep_kernel<<<12, 256, 0, stream>>>(ll, gl, out_leaf, out_gate, ws_leaf, ws_gate);
    tree16_kernel<<<1024, 512, 0, stream>>>(x, ws_leaf, ws_gate, out0, cplx);
  } else {
    tree_fb_kernel<<<512, 512, 0, stream>>>(x, ll, gl, out0, cplx);
    probs_fb_kernel<<<12, 256, 0, stream>>>(ll, gl, out_leaf, out_gate);
  }
}

// Round 5
// 58.753 us; speedup vs baseline: 1.4263x; 1.4263x over previous
//
#include <hip/hip_runtime.h>
#include <math.h>

#define EPSF     1.1920928955078125e-07f   // float32 eps
#define BYPASSF  0.9999998807907104f       // 1 - eps
#define CLAMPF   1e30f
#define NBATCH   32768

// split constants
#define INV2PI_HI 0.15915493667125701904f  // fp32(1/2pi)
#define INV2PI_LO 6.42063831e-9f           // 1/2pi - hi
#define L2E_HI    1.44269502162933349609f  // fp32(log2 e)
#define L2E_LO    1.92596299e-8f           // log2e - hi
#define LN2F      0.69314718055994530942f
#define PI_F      3.14159274101257324219f
#define PIO2_F    1.57079637050628662109f

// geometry: 16 subtrees/element, depth-6 local fold, block=1024 (64 elements), grid=512
#define SLAB_SRC 504                       // floats per subtree slab in d_ws (63 steps * 8)
#define SLAB_LDS 508                       // floats per slab in LDS (start banks step 28*lt mod 32 -> 2-way)
#define GDS_FLOATS (16 * SLAB_LDS + 120)   // + 15 top gates * 8 = 8248 floats = 32,992 B
#define LW_F4_STRIDE 65                    // leaf slab stride in float4 (start banks 4*lt mod 32 -> 2-way)
#define WS_NEED ((4096 + 8184) * 4)        // bytes: leaves + gates

struct C2 { float r, i; };

__device__ __forceinline__ float fixv(float v) {
  float c = fminf(fmaxf(v, -CLAMPF), CLAMPF);
  return (v != v) ? 0.0f : c;
}

__device__ __attribute__((noinline)) float2 slow_sincos(float y) {
  return make_float2(sinf(y), cosf(y));
}

__device__ __forceinline__ void softmax3_store(float a, float b, float c, float* out) {
  float m = fmaxf(a, fmaxf(b, c));
  float e0 = expf(a - m), e1 = expf(b - m), e2 = expf(c - m);
  float s = (e0 + e1) + e2;
  out[0] = e0 / s; out[1] = e1 / s; out[2] = e2 / s;
}

__device__ __forceinline__ void softmax4(const float* __restrict__ in, float* out) {
  float a = in[0], b = in[1], c = in[2], d = in[3];
  float m = fmaxf(fmaxf(a, b), fmaxf(c, d));
  float e0 = expf(a - m), e1 = expf(b - m), e2 = expf(c - m), e3 = expf(d - m);
  float s = ((e0 + e1) + e2) + e3;
  out[0] = e0 / s; out[1] = e1 / s; out[2] = e2 / s; out[3] = e3 / s;
}

// bypass/eps folding (exact: probs sum to 1 -> at most one can exceed 1-eps)
__device__ __forceinline__ void fold_gate(float* p) {
  if (p[3] <= EPSF) p[3] = 0.0f;
  if (p[0] > BYPASSF)      { p[0]=1.f; p[1]=0.f; p[2]=0.f; p[3]=0.f; }
  else if (p[1] > BYPASSF) { p[0]=0.f; p[1]=1.f; p[2]=0.f; p[3]=0.f; }
  else if (p[2] > BYPASSF) { p[0]=0.f; p[1]=0.f; p[2]=1.f; p[3]=0.f; }
}

__device__ __forceinline__ float exp_core(float xe, int* n_out) {
  float nf = rintf(xe * 1.4426950408889634f);
  float f  = fmaf(xe, L2E_HI, -nf);
  f        = fmaf(xe, L2E_LO, f);
  *n_out   = (int)nf;
  return __builtin_amdgcn_exp2f(f);
}

// clamp(cexp(blend(gl, L)) - clog(blend(gr, R))) -- general complex path
__device__ __forceinline__ C2 combine2(const float* __restrict__ g8, C2 L, C2 R, float x0, float x1) {
  float4 gl = *(const float4*)(g8);
  float4 gr = *(const float4*)(g8 + 4);
  float lr_ = fmaf(gl.w, L.r, gl.x) + fmaf(gl.z, x1, gl.y * x0);
  float li_ = gl.w * L.i;
  float rr_ = fmaf(gr.w, R.r, gr.x) + fmaf(gr.z, x1, gr.y * x0);
  float ri_ = gr.w * R.i;

  // sincos via revolution-domain Cody-Waite feeding HW v_sin/v_cos
  float sy, cy;
  {
    float nf = rintf(li_ * 0.15915494309189535f);
    float rv = fmaf(li_, INV2PI_HI, -nf);
    rv       = fmaf(li_, INV2PI_LO, rv);
    sy = __builtin_amdgcn_sinf(rv);
    cy = __builtin_amdgcn_cosf(rv);
    if (fabsf(li_) > 20000.0f) { float2 sc = slow_sincos(li_); sy = sc.x; cy = sc.y; }
  }

  // exp(lr_) scaled: covers ldexp_cexpf region and over/underflow
  float xe = fminf(fmaxf(lr_, -200.0f), 200.0f);
  int ne;
  float eh = exp_core(xe, &ne);
  float er = __builtin_amdgcn_ldexpf(eh * cy, ne);
  float ei = __builtin_amdgcn_ldexpf(eh * sy, ne);

  // clog: shared s = mn/mx for log-hypot and atan2
  float ax = fabsf(rr_), ay = fabsf(ri_);
  float mx = fmaxf(ax, ay), mn = fminf(ax, ay);
  float s  = (mx == 0.0f) ? 0.0f : mn * __builtin_amdgcn_rcpf(mx);
  float z  = s * s;
  float lr = LN2F * fmaf(0.5f, __builtin_amdgcn_logf(z + 1.0f), __builtin_amdgcn_logf(mx));
  float u =              0.00282363896f;
  u = fmaf(u, z, -0.0159569028f);
  u = fmaf(u, z,  0.0425049886f);
  u = fmaf(u, z, -0.0748900920f);
  u = fmaf(u, z,  0.1063479334f);
  u = fmaf(u, z, -0.1420273631f);
  u = fmaf(u, z,  0.1999269574f);
  u = fmaf(u, z, -0.3333310186f);
  float at = fmaf(s * z, u, s);
  at = (ay > ax)    ? (PIO2_F - at) : at;
  at = (rr_ < 0.0f) ? (PI_F   - at) : at;
  float li = copysignf(at, ri_);

  C2 o; o.r = fixv(er - lr); o.i = fixv(ei - li);
  return o;
}

// level-1 specialization: both children are real leaves (imag exactly 0)
__device__ __forceinline__ C2 combine_l1(const float* __restrict__ g8, float Lr, float Rr,
                                         float x0, float x1) {
  float4 gl = *(const float4*)(g8);
  float4 gr = *(const float4*)(g8 + 4);
  float lr_ = fmaf(gl.w, Lr, gl.x) + fmaf(gl.z, x1, gl.y * x0);
  float rr_ = fmaf(gr.w, Rr, gr.x) + fmaf(gr.z, x1, gr.y * x0);

  float xe = fminf(fmaxf(lr_, -200.0f), 200.0f);
  int ne;
  float eh = exp_core(xe, &ne);
  float er = __builtin_amdgcn_ldexpf(eh, ne);

  float lr = LN2F * __builtin_amdgcn_logf(fabsf(rr_));
  C2 o;
  o.r = fminf(fmaxf(er - lr, -CLAMPF), CLAMPF);
  o.i = (rr_ < 0.0f) ? -PI_F : 0.0f;
  return o;
}

// ---------------- prep: softmax + fold + DFS reorder into d_ws, plus probs outputs ----------------
__global__ __launch_bounds__(256) void prep_kernel(
    const float* __restrict__ leaf_logits,
    const float* __restrict__ gate_logits,
    float* __restrict__ out_leaf,   // 1024 x 3 raw
    float* __restrict__ out_gate,   // 2046 x 4 raw
    float* __restrict__ ws_leaf,    // 1024 float4 {w0,w1,w2,0}
    float* __restrict__ ws_gate) {  // 16*504 (DFS levels 1..6) + 15*8 (top)
  int i = blockIdx.x * 256 + threadIdx.x;
  if (i < 1024) {
    float p[3];
    softmax3_store(leaf_logits[i * 3], leaf_logits[i * 3 + 1], leaf_logits[i * 3 + 2], p);
    out_leaf[i * 3] = p[0]; out_leaf[i * 3 + 1] = p[1]; out_leaf[i * 3 + 2] = p[2];
    ((float4*)ws_leaf)[i] = make_float4(p[0], p[1], p[2], 0.0f);
  } else if (i < 1024 + 2046) {
    int j = i - 1024;                  // gate half-row 0..2045
    int g = j >> 1, half = j & 1;
    float p[4];
    softmax4(gate_logits + j * 4, p);
    ((float4*)out_gate)[j] = make_float4(p[0], p[1], p[2], p[3]);
    fold_gate(p);
    int di;
    if (g < 1008) {                    // levels 1..6 -> per-subtree DFS order
      int z  = 1024 - g;
      int k  = __clz(z - 1) - 21;      // 1..6
      int pp = g - (1024 - (2048 >> k));
      int t  = pp >> (6 - k);
      int pl = pp & ((1 << (6 - k)) - 1);
      int L  = ((pl + 1) << k) - 1;
      int step = L - __popc(L) + (k - 1);  // 0..62
      di = t * SLAB_SRC + step * 8;
    } else {
      di = 16 * SLAB_SRC + (g - 1008) * 8; // top 15 gates flat
    }
    ((float4*)(ws_gate + di))[half] = make_float4(p[0], p[1], p[2], p[3]);
  }
}

// ---------------- fast tree: 16 lanes/element, gates AND leaves in LDS, block=1024 ----------------
__global__ __launch_bounds__(1024, 8) void tree16_kernel(
    const float* __restrict__ x,
    const float* __restrict__ ws_leaf,
    const float* __restrict__ ws_gate,
    float* __restrict__ out0, int cplx) {

  __shared__ __align__(16) float gds[GDS_FLOATS];           // 32,992 B
  __shared__ __align__(16) float lwds[16 * LW_F4_STRIDE * 4]; // 16,640 B
  const int tid = threadIdx.x;

  // copy gate table ws -> LDS, re-striding slabs 504 -> 508 (126 -> 127 float4)
  {
    float4* g4 = (float4*)gds;
    const float4* s4 = (const float4*)ws_gate;
    for (int c = tid; c < 2016; c += 1024) {
      int t = c / 126;
      int r = c - t * 126;
      g4[t * 127 + r] = s4[c];
    }
    if (tid < 30) g4[2032 + tid] = s4[2016 + tid];   // top gates
    // leaf table: float4 index l -> slab lt=l>>6, skewed stride 65
    float4* l4 = (float4*)lwds;
    const float4* sl = (const float4*)ws_leaf;
    if (tid < 1024) l4[tid + (tid >> 6)] = sl[tid];
  }
  __syncthreads();

  const int gtid = blockIdx.x * 1024 + tid;
  const int e  = gtid >> 4;          // batch element
  const int lt = tid & 15;           // subtree index
  const float2 xv = ((const float2*)x)[e];
  const float x0 = xv.x, x1 = xv.y;
  const float* gb  = &gds[lt * SLAB_LDS];
  const float* tds = &gds[16 * SLAB_LDS];
  const float4* lwp = (const float4*)lwds + lt * LW_F4_STRIDE;

  C2 p1, p2, p3, p4, p5;             // pending left siblings, levels 2..6
  C2 res; res.r = 0.0f; res.i = 0.0f;
  int step = 0;

  #pragma unroll 2
  for (int h = 0; h < 32; ++h) {
    float4 w0 = lwp[2 * h];
    float4 w1 = lwp[2 * h + 1];
    float a = fmaf(w0.z, x1, fmaf(w0.y, x0, w0.x));
    float b = fmaf(w1.z, x1, fmaf(w1.y, x0, w1.x));
    C2 cur = combine_l1(gb + step * 8, a, b, x0, x1); step++;
    if (!(h & 1))  { p1 = cur; continue; }
    cur = combine2(gb + step * 8, p1, cur, x0, x1); step++;
    if (!(h & 2))  { p2 = cur; continue; }
    cur = combine2(gb + step * 8, p2, cur, x0, x1); step++;
    if (!(h & 4))  { p3 = cur; continue; }
    cur = combine2(gb + step * 8, p3, cur, x0, x1); step++;
    if (!(h & 8))  { p4 = cur; continue; }
    cur = combine2(gb + step * 8, p4, cur, x0, x1); step++;
    if (!(h & 16)) { p5 = cur; continue; }
    cur = combine2(gb + step * 8, p5, cur, x0, x1); step++;
    res = cur;                       // level-6 subtree root
  }

  // top 4 levels across the 16 lanes of this element (gate rows 1008..1022 -> tds 0..14)
  C2 v = res;
  { C2 o; o.r = __shfl_xor(v.r, 1); o.i = __shfl_xor(v.i, 1);
    C2 L = (lt & 1) ? o : v, R = (lt & 1) ? v : o;
    v = combine2(tds + (lt >> 1) * 8, L, R, x0, x1); }
  { C2 o; o.r = __shfl_xor(v.r, 2); o.i = __shfl_xor(v.i, 2);
    C2 L = (lt & 2) ? o : v, R = (lt & 2) ? v : o;
    v = combine2(tds + (8 + (lt >> 2)) * 8, L, R, x0, x1); }
  { C2 o; o.r = __shfl_xor(v.r, 4); o.i = __shfl_xor(v.i, 4);
    C2 L = (lt & 4) ? o : v, R = (lt & 4) ? v : o;
    v = combine2(tds + (12 + (lt >> 3)) * 8, L, R, x0, x1); }
  { C2 o; o.r = __shfl_xor(v.r, 8); o.i = __shfl_xor(v.i, 8);
    C2 L = (lt & 8) ? o : v, R = (lt & 8) ? v : o;
    v = combine2(tds + 14 * 8, L, R, x0, x1); }

  if (lt == 0) {
    if (cplx) { out0[2 * e] = v.r; out0[2 * e + 1] = v.i; }
    else      { out0[e] = v.r; }
  }
}

// ---------------- fallback (R3 kernels, used only if ws_size is too small) ----------------
#define GSTRIDE  1020
#define LSTRIDE  516

__device__ __forceinline__ void store_gate_fb(const float* __restrict__ in, float* __restrict__ out) {
  float p[4];
  softmax4(in, p);
  fold_gate(p);
  out[0]=p[0]; out[1]=p[1]; out[2]=p[2]; out[3]=p[3];
}

__global__ __launch_bounds__(512) void tree_fb_kernel(
    const float* __restrict__ x,
    const float* __restrict__ leaf_logits,
    const float* __restrict__ gate_logits,
    float* __restrict__ out0, int cplx) {

  __shared__ __align__(16) float gds[8 * GSTRIDE];
  __shared__ __align__(16) float tds[7 * 8];
  __shared__ __align__(16) float lw[8 * LSTRIDE];
  const int tid = threadIdx.x;

  for (int l = tid; l < 1024; l += 512) {
    float p[3];
    softmax3_store(leaf_logits[l * 3], leaf_logits[l * 3 + 1], leaf_logits[l * 3 + 2], p);
    *(float4*)&lw[(l >> 7) * LSTRIDE + (l & 127) * 4] = make_float4(p[0], p[1], p[2], 0.0f);
  }
  for (int g = tid; g < 1016; g += 512) {
    int z  = 1024 - g;
    int k  = __clz(z - 1) - 21;
    int p  = g - (1024 - (2048 >> k));
    int t  = p >> (7 - k);
    int pl = p & ((1 << (7 - k)) - 1);
    int L  = ((pl + 1) << k) - 1;
    int step = L - __popc(L) + (k - 1);
    float* dst = &gds[t * GSTRIDE + step * 8];
    store_gate_fb(gate_logits + g * 8,     dst);
    store_gate_fb(gate_logits + g * 8 + 4, dst + 4);
  }
  if (tid < 7) {
    int g = 1016 + tid;
    store_gate_fb(gate_logits + g * 8,     &tds[tid * 8]);
    store_gate_fb(gate_logits + g * 8 + 4, &tds[tid * 8 + 4]);
  }
  __syncthreads();

  const int gtid = blockIdx.x * 512 + tid;
  const int e  = gtid >> 3;
  const int lt = tid & 7;
  const float2 xv = ((const float2*)x)[e];
  const float x0 = xv.x, x1 = xv.y;
  const float* gb = &gds[lt * GSTRIDE];
  const float* lb = &lw[lt * LSTRIDE];

  C2 p1, p2, p3, p4, p5, p6;
  C2 res; res.r = 0.0f; res.i = 0.0f;
  int step = 0;

  #pragma unroll 2
  for (int h = 0; h < 64; ++h) {
    float4 w0 = *(const float4*)&lb[(2 * h) * 4];
    float4 w1 = *(const float4*)&lb[(2 * h + 1) * 4];
    float a = fmaf(w0.z, x1, fmaf(w0.y, x0, w0.x));
    float b = fmaf(w1.z, x1, fmaf(w1.y, x0, w1.x));
    C2 cur = combine_l1(gb + step * 8, a, b, x0, x1); step++;
    if (!(h & 1))  { p1 = cur; continue; }
    cur = combine2(gb + step * 8, p1, cur, x0, x1); step++;
    if (!(h & 2))  { p2 = cur; continue; }
    cur = combine2(gb + step * 8, p2, cur, x0, x1); step++;
    if (!(h & 4))  { p3 = cur; continue; }
    cur = combine2(gb + step * 8, p3, cur, x0, x1); step++;
    if (!(h & 8))  { p4 = cur; continue; }
    cur = combine2(gb + step * 8, p4, cur, x0, x1); step++;
    if (!(h & 16)) { p5 = cur; continue; }
    cur = combine2(gb + step * 8, p5, cur, x0, x1); step++;
    if (!(h & 32)) { p6 = cur; continue; }
    cur = combine2(gb + step * 8, p6, cur, x0, x1); step++;
    res = cur;
  }

  C2 v = res;
  { C2 o; o.r = __shfl_xor(v.r, 1); o.i = __shfl_xor(v.i, 1);
    C2 L = (lt & 1) ? o : v, R = (lt & 1) ? v : o;
    v = combine2(&tds[(lt >> 1) * 8], L, R, x0, x1); }
  { C2 o; o.r = __shfl_xor(v.r, 2); o.i = __shfl_xor(v.i, 2);
    C2 L = (lt & 2) ? o : v, R = (lt & 2) ? v : o;
    v = combine2(&tds[(4 + (lt >> 2)) * 8], L, R, x0, x1); }
  { C2 o; o.r = __shfl_xor(v.r, 4); o.i = __shfl_xor(v.i, 4);
    C2 L = (lt & 4) ? o : v, R = (lt & 4) ? v : o;
    v = combine2(&tds[6 * 8], L, R, x0, x1); }

  if (lt == 0) {
    if (cplx) { out0[2 * e] = v.r; out0[2 * e + 1] = v.i; }
    else      { out0[e] = v.r; }
  }
}

__global__ __launch_bounds__(256) void probs_fb_kernel(
    const float* __restrict__ leaf_logits,
    const float* __restrict__ gate_logits,
    float* __restrict__ out_leaf,
    float* __restrict__ out_gate) {
  int i = blockIdx.x * 256 + threadIdx.x;
  if (i < 1024) {
    softmax3_store(leaf_logits[i * 3], leaf_logits[i * 3 + 1], leaf_logits[i * 3 + 2],
                   &out_leaf[i * 3]);
  } else if (i < 1024 + 2046) {
    int j = i - 1024;
    float p[4];
    softmax4(gate_logits + j * 4, p);
    ((float4*)out_gate)[j] = make_float4(p[0], p[1], p[2], p[3]);
  }
}

extern "C" void kernel_launch(void* const* d_in, const int* in_sizes, int n_in,
                              void* d_out, int out_size, void* d_ws, size_t ws_size,
                              hipStream_t stream) {
  const float* x  = (const float*)d_in[0];   // (32768, 2)
  const float* ll = (const float*)d_in[1];   // (1024, 3)
  const float* gl = (const float*)d_in[2];   // (1023, 2, 4)
  float* out0 = (float*)d_out;

  int S = out_size - (3072 + 8184);          // complex chunk: 2*32768 interleaved or 32768 real
  int cplx = (S >= 2 * NBATCH) ? 1 : 0;
  float* out_leaf = out0 + S;
  float* out_gate = out_leaf + 3072;

  if (ws_size >= (size_t)WS_NEED) {
    float* ws_leaf = (float*)d_ws;           // 4096 floats
    float* ws_gate = ws_leaf + 4096;         // 8184 floats
    prep_kernel<<<12, 256, 0, stream>>>(ll, gl, out_leaf, out_gate, ws_leaf, ws_gate);
    tree16_kernel<<<512, 1024, 0, stream>>>(x, ws_leaf, ws_gate, out0, cplx);
  } else {
    tree_fb_kernel<<<512, 512, 0, stream>>>(x, ll, gl, out0, cplx);
    probs_fb_kernel<<<12, 256, 0, stream>>>(ll, gl, out_leaf, out_gate);
  }
}